// Round 12
// baseline (197.999 us; speedup 1.0000x reference)
//
#include <hip/hip_runtime.h>
#include <hip/hip_bf16.h>

// GraphSAGE 2-layer, N=100000, E=1200000, D: 64 -> 64 -> 32, fp32 in/out.
// R12: two-phase graph build. R11's single-pass bucket_fill streamed 9.6MB
// of edges through each XCD's 4MB L2, evicting partially-filled dirty nbr
// lines (~11 writebacks/line, 56MB HBM write for 4.8MB payload). Phase A
// compacts edges into 8 partition queues with COALESCED writes (8 atomics
// per block, not per edge: packed-u64 per-thread histogram + one LDS scan).
// Phase B: XCD p scatters only its own 1.2MB queue into its L2-resident
// cnt/nbr slices -> dirty lines stay resident, ~1 writeback each.
// Slot buckets nbr[n][40]+cnt (R11). Gather: 8-rows-in-flight uint4 (R9).
// Dense: 4-wave j-split (R8). bf16 activations (R6). XCD %8 mapping (R7).

#define D1 64
#define NPART 8
#define MAXSLOT 40
#define PSIZE 12544          // 8*12544 = 100352 >= N; constexpr -> magic-mul div
#define QCAP 160000          // per-partition queue cap; E/8=150K, sigma~362
#define BE 1280              // edges per compaction block (256 thr x 5)

static __device__ __forceinline__ float bf2f(ushort u) {
    unsigned int x = ((unsigned int)u) << 16;
    return __uint_as_float(x);
}
static __device__ __forceinline__ ushort f2bf(float f) {
    union { __hip_bfloat16 b; ushort u; } cv;
    cv.b = __float2bfloat16(f);   // RNE
    return cv.u;
}
static __device__ __forceinline__ float lo2f(unsigned u) {
    return __uint_as_float(u << 16);
}
static __device__ __forceinline__ float hi2f(unsigned u) {
    return __uint_as_float(u & 0xffff0000u);
}
static __device__ __forceinline__ unsigned packbf(float x, float y) {
    return (unsigned)f2bf(x) | ((unsigned)f2bf(y) << 16);
}

// ---- phase A: compact edges into 8 partition queues (coalesced writes) --
// Per-thread counts packed as 4x16-bit fields in two u64s; one LDS scan of
// the packed pair gives per-thread exclusive offsets for all 8 partitions.

__global__ __launch_bounds__(256)
void compact_edges(const int* __restrict__ src, const int* __restrict__ dst,
                   int* __restrict__ tail, int2* __restrict__ queue, int E) {
    __shared__ unsigned long long slo[256], shi[256];
    __shared__ int bcast[8];
    int tid = threadIdx.x;
    int bstart = blockIdx.x * BE;

    int ds[5], ss[5];
    unsigned long long clo = 0, chi = 0;
    #pragma unroll
    for (int k = 0; k < 5; ++k) {
        int e = bstart + k * 256 + tid;
        int d = -1, s = 0;
        if (e < E) { d = dst[e]; s = src[e]; }
        ds[k] = d; ss[k] = s;
        if (d >= 0) {
            int part = d / PSIZE;
            unsigned long long inc = 1ull << (16 * (part & 3));
            if (part < 4) clo += inc; else chi += inc;
        }
    }
    slo[tid] = clo; shi[tid] = chi;
    __syncthreads();
    for (int off = 1; off < 256; off <<= 1) {
        unsigned long long alo = 0, ahi = 0;
        if (tid >= off) { alo = slo[tid - off]; ahi = shi[tid - off]; }
        __syncthreads();
        slo[tid] += alo; shi[tid] += ahi;
        __syncthreads();
    }
    unsigned long long elo = slo[tid] - clo, ehi = shi[tid] - chi; // exclusive
    unsigned long long tlo = slo[255], thi = shi[255];             // block totals
    if (tid < 8) {
        int tot = (int)((((tid < 4) ? tlo : thi) >> (16 * (tid & 3))) & 0xffffull);
        bcast[tid] = atomicAdd(&tail[tid], tot);
    }
    __syncthreads();

    unsigned long long rlo = 0, rhi = 0;   // own running counts
    #pragma unroll
    for (int k = 0; k < 5; ++k) {
        int d = ds[k];
        if (d >= 0) {
            int part = d / PSIZE;
            int sh = 16 * (part & 3);
            unsigned long long eP = (part < 4) ? elo : ehi;
            unsigned long long rP = (part < 4) ? rlo : rhi;
            int off = (int)((eP >> sh) & 0xffffull) + (int)((rP >> sh) & 0xffffull);
            int pos = bcast[part] + off;
            if (pos < QCAP) queue[(size_t)part * QCAP + pos] = make_int2(ss[k], d);
            unsigned long long inc = 1ull << sh;
            if (part < 4) rlo += inc; else rhi += inc;
        }
    }
}

// ---- phase B: XCD-local scatter from own queue into slot buckets --------

__global__ __launch_bounds__(256)
void bucket_fill_local(const int2* __restrict__ queue, const int* __restrict__ tail,
                       int* __restrict__ cnt, int* __restrict__ nbr) {
    int p     = blockIdx.x & (NPART - 1);
    int chunk = blockIdx.x >> 3;
    int nch   = gridDim.x >> 3;
    int nt = min(tail[p], QCAP);
    int ce = (nt + nch - 1) / nch;
    int e0 = chunk * ce;
    int e1 = min(nt, e0 + ce);
    const int2* q = queue + (size_t)p * QCAP;
    for (int e = e0 + threadIdx.x; e < e1; e += 256) {
        int2 pr = q[e];
        int pos = atomicAdd(&cnt[pr.y], 1);
        if (pos < MAXSLOT) nbr[(size_t)pr.y * MAXSLOT + pos] = pr.x;
    }
}

// ---- fp32 -> bf16 activation convert ------------------------------------

__global__ __launch_bounds__(256)
void cvt_bf16(const float* __restrict__ in, ushort* __restrict__ outp, int n4) {
    int i = blockIdx.x * 256 + threadIdx.x;   // one float4 -> ushort4
    if (i < n4) {
        float4 v = *(const float4*)&in[(size_t)i * 4];
        ushort4 u;
        u.x = f2bf(v.x); u.y = f2bf(v.y); u.z = f2bf(v.z); u.w = f2bf(v.w);
        *(ushort4*)&outp[(size_t)i * 4] = u;
    }
}

// ---- gather: mean of bf16 neighbor rows. Wave per node. ------------------
// Lane (r,c) = (lane>>3, lane&7): slot r covers neighbor i+r, lane loads
// uint4 = 8 bf16 at quad c -> one instruction fetches 8 full rows (1KB).
// Unroll x2 (16 rows in flight). Reduce slots via shfl_xor 8/16/32.

#define ACC8(u) do { \
    a0 += lo2f((u).x); a1 += hi2f((u).x); \
    a2 += lo2f((u).y); a3 += hi2f((u).y); \
    a4 += lo2f((u).z); a5 += hi2f((u).z); \
    a6 += lo2f((u).w); a7 += hi2f((u).w); } while (0)

__global__ __launch_bounds__(256)
void gather_mean8(const ushort* __restrict__ feat,
                  const int* __restrict__ cnt,
                  const int* __restrict__ nbr,
                  ushort* __restrict__ mean, int N) {
    int wid  = (blockIdx.x * 256 + threadIdx.x) >> 6;
    int lane = threadIdx.x & 63;
    if (wid >= N) return;
    int deg = cnt[wid];
    int m = min(deg, MAXSLOT);
    const int* nb = nbr + (size_t)wid * MAXSLOT;
    int r = lane >> 3;          // neighbor slot 0..7
    int c = lane & 7;           // uint4 quad within 64-feature row
    const uint4* f4 = (const uint4*)feat;

    float a0 = 0, a1 = 0, a2 = 0, a3 = 0, a4 = 0, a5 = 0, a6 = 0, a7 = 0;
    int i = 0;
    for (; i + 16 <= m; i += 16) {
        int e0 = nb[i + r];
        int e1 = nb[i + 8 + r];
        uint4 u0 = f4[(size_t)e0 * 8 + c];
        uint4 u1 = f4[(size_t)e1 * 8 + c];
        ACC8(u0);
        ACC8(u1);
    }
    if (i + 8 <= m) {
        int e0 = nb[i + r];
        uint4 u0 = f4[(size_t)e0 * 8 + c];
        ACC8(u0);
        i += 8;
    }
    if (i < m) {
        int idx = i + r;
        int e = nb[(idx < m) ? idx : (m - 1)];
        uint4 u = f4[(size_t)e * 8 + c];
        if (idx < m) ACC8(u);
    }

    // reduce across the 8 slots (lane bits 3,4,5)
    a0 += __shfl_xor(a0, 8, 64); a0 += __shfl_xor(a0, 16, 64); a0 += __shfl_xor(a0, 32, 64);
    a1 += __shfl_xor(a1, 8, 64); a1 += __shfl_xor(a1, 16, 64); a1 += __shfl_xor(a1, 32, 64);
    a2 += __shfl_xor(a2, 8, 64); a2 += __shfl_xor(a2, 16, 64); a2 += __shfl_xor(a2, 32, 64);
    a3 += __shfl_xor(a3, 8, 64); a3 += __shfl_xor(a3, 16, 64); a3 += __shfl_xor(a3, 32, 64);
    a4 += __shfl_xor(a4, 8, 64); a4 += __shfl_xor(a4, 16, 64); a4 += __shfl_xor(a4, 32, 64);
    a5 += __shfl_xor(a5, 8, 64); a5 += __shfl_xor(a5, 16, 64); a5 += __shfl_xor(a5, 32, 64);
    a6 += __shfl_xor(a6, 8, 64); a6 += __shfl_xor(a6, 16, 64); a6 += __shfl_xor(a6, 32, 64);
    a7 += __shfl_xor(a7, 8, 64); a7 += __shfl_xor(a7, 16, 64); a7 += __shfl_xor(a7, 32, 64);

    if (r == 0) {               // lanes 0..7 write the 128B mean row
        float inv = 1.0f / fmaxf((float)deg, 1.0f);
        uint4 o;
        o.x = packbf(a0 * inv, a1 * inv);
        o.y = packbf(a2 * inv, a3 * inv);
        o.z = packbf(a4 * inv, a5 * inv);
        o.w = packbf(a6 * inv, a7 * inv);
        ((uint4*)mean)[(size_t)wid * 8 + c] = o;
    }
}

// ---- dense: out[n][j] = act(sum_k Am[n][k] Wm[k][j] + Ax[n][k] Wx[k][j] + b[j])
// Block = 256 threads = 64 nodes; lane = node. Wave w computes j-slice
// [w*DOUT/4, (w+1)*DOUT/4). Shared bf16 A-tile ta[128][66] (Am k=0..63,
// Ax k=64..127). Weights wave-uniform -> scalar loads. Epilogue reuses
// LDS as fp32 [DOUT][65] transpose tile.

#define TA_STRIDE 66

template <int DOUT, bool RELU, bool OUTBF>
__global__ __launch_bounds__(256)
void dense_sage(const ushort* __restrict__ Am,    // mean [N][64] bf16
                const ushort* __restrict__ Ax,    // x or h [N][64] bf16
                const float* __restrict__ Wm,     // [64][DOUT]
                const float* __restrict__ Wx,     // [64][DOUT]
                const float* __restrict__ bias,   // [DOUT]
                void* __restrict__ outp, int N) {
    constexpr int JW = DOUT / 4;                  // j per wave: 16 or 8
    __shared__ char smraw[128 * TA_STRIDE * 2];   // 16.9 KB (>= DOUT*65*4)
    ushort* ta = (ushort*)smraw;
    float*  to = (float*)smraw;

    int tid  = threadIdx.x;
    int w    = tid >> 6;
    int lane = tid & 63;
    int n0 = blockIdx.x * 64;

    // stage 128 logical rows (64 Am + 64 Ax) x 64 cols, transposed:
    // ta[k][node], k = (isAx ? 64 : 0) + col. 16 threads cover one 128B row.
    #pragma unroll
    for (int i = 0; i < 8; ++i) {
        int flat = i * 256 + tid;        // 0..2047 ushort4-chunks
        int row  = flat >> 4;            // 0..127
        int c4   = (flat & 15) * 4;      // 0..60
        const ushort* A = (row < 64) ? Am : Ax;
        int node = row & 63;
        int grow = n0 + node;
        ushort4 u = make_ushort4(0, 0, 0, 0);
        if (grow < N) u = *(const ushort4*)&A[(size_t)grow * D1 + c4];
        int kb = ((row < 64) ? 0 : 64) + c4;
        ta[(kb + 0) * TA_STRIDE + node] = u.x;
        ta[(kb + 1) * TA_STRIDE + node] = u.y;
        ta[(kb + 2) * TA_STRIDE + node] = u.z;
        ta[(kb + 3) * TA_STRIDE + node] = u.w;
    }
    __syncthreads();

    int jb = __builtin_amdgcn_readfirstlane(w * JW);
    float c[JW];
    #pragma unroll
    for (int j = 0; j < JW; ++j) c[j] = bias[jb + j];

    #pragma unroll 4
    for (int k = 0; k < 64; ++k) {
        float a = bf2f(ta[k * TA_STRIDE + lane]);
        #pragma unroll
        for (int j = 0; j < JW; ++j)
            c[j] = fmaf(a, Wm[k * DOUT + jb + j], c[j]);   // wave-uniform idx
    }
    #pragma unroll 4
    for (int k = 0; k < 64; ++k) {
        float a = bf2f(ta[(64 + k) * TA_STRIDE + lane]);
        #pragma unroll
        for (int j = 0; j < JW; ++j)
            c[j] = fmaf(a, Wx[k * DOUT + jb + j], c[j]);
    }

    if (RELU) {
        #pragma unroll
        for (int j = 0; j < JW; ++j) c[j] = fmaxf(c[j], 0.0f);
    }

    __syncthreads();   // A-tile fully consumed -> reuse LDS as out-tile
    #pragma unroll
    for (int j = 0; j < JW; ++j) to[(jb + j) * 65 + lane] = c[j];
    __syncthreads();

    // coalesced store: 64 rows x DOUT, vec4 chunks
    #pragma unroll
    for (int i = 0; i < DOUT / 16; ++i) {
        int flat = i * 256 + tid;            // quad index
        int node = flat / (DOUT / 4);
        int q    = flat % (DOUT / 4);
        int grow = n0 + node;
        if (grow < N) {
            float vx = to[(q * 4 + 0) * 65 + node];
            float vy = to[(q * 4 + 1) * 65 + node];
            float vz = to[(q * 4 + 2) * 65 + node];
            float vw = to[(q * 4 + 3) * 65 + node];
            size_t o = (size_t)grow * DOUT + q * 4;
            if (OUTBF) {
                ushort4 u;
                u.x = f2bf(vx); u.y = f2bf(vy); u.z = f2bf(vz); u.w = f2bf(vw);
                *(ushort4*)&((ushort*)outp)[o] = u;
            } else {
                *(float4*)&((float*)outp)[o] = make_float4(vx, vy, vz, vw);
            }
        }
    }
}

// ---- launch -------------------------------------------------------------

extern "C" void kernel_launch(void* const* d_in, const int* in_sizes, int n_in,
                              void* d_out, int out_size, void* d_ws, size_t ws_size,
                              hipStream_t stream) {
    const float* x   = (const float*)d_in[0];
    const int*   ei  = (const int*)d_in[1];
    const float* W1l = (const float*)d_in[2];
    const float* W1r = (const float*)d_in[3];
    const float* b1  = (const float*)d_in[4];
    const float* W2l = (const float*)d_in[5];
    const float* W2r = (const float*)d_in[6];
    const float* b2  = (const float*)d_in[7];
    float* out = (float*)d_out;

    int N = in_sizes[0] / D1;
    int E = in_sizes[1] / 2;
    const int* src = ei;
    const int* dst = ei + E;

    char* ws = (char*)d_ws;
    auto alignup = [](size_t v) { return (v + 255) & ~(size_t)255; };
    size_t off = 0;
    int*    cnt   = (int*)(ws + off);
    int*    tail  = cnt + N;            // 8 ints right after cnt (one memset)
    off += alignup((size_t)(N + 64) * 4);
    int2*   queue = (int2*)(ws + off);  off += alignup((size_t)NPART * QCAP * 8);
    int*    nbr   = (int*)(ws + off);   off += alignup((size_t)N * MAXSLOT * 4);
    ushort* xh    = (ushort*)(ws + off); off += alignup((size_t)N * D1 * 2);
    ushort* hh    = (ushort*)(ws + off); off += alignup((size_t)N * D1 * 2);
    // layer-1 mean lives in d_out (fully overwritten by dense2 at the end);
    // layer-2 mean reuses xh (dead after dense1).
    ushort* mean1 = (ushort*)d_out;     // N*64*2B = 12.8MB == out_size bytes
    ushort* mean2 = xh;

    int gb = (N + 3) / 4;         // gather: wave per node, 4 waves/block
    int db = (N + 63) / 64;       // dense: 64 nodes/block, 4 j-slice waves
    int cb = ((N * D1 / 4) + 255) / 256;
    int ab = (E + BE - 1) / BE;   // compaction blocks (938)
    int bb = NPART * 128;         // fill blocks: 8 partitions x 128 chunks

    hipMemsetAsync(cnt, 0, (size_t)(N + 64) * 4, stream);   // cnt + tail
    compact_edges<<<ab, 256, 0, stream>>>(src, dst, tail, queue, E);
    bucket_fill_local<<<bb, 256, 0, stream>>>(queue, tail, cnt, nbr);
    cvt_bf16<<<cb, 256, 0, stream>>>(x, xh, N * D1 / 4);

    gather_mean8<<<gb, 256, 0, stream>>>(xh, cnt, nbr, mean1, N);
    dense_sage<64, true, true ><<<db, 256, 0, stream>>>(mean1, xh, W1l, W1r, b1, hh, N);
    gather_mean8<<<gb, 256, 0, stream>>>(hh, cnt, nbr, mean2, N);
    dense_sage<32, false, false><<<db, 256, 0, stream>>>(mean2, hh, W2l, W2r, b2, out, N);
}

// Round 13
// 190.118 us; speedup vs baseline: 1.0415x; 1.0415x over previous
//
#include <hip/hip_runtime.h>
#include <hip/hip_bf16.h>

// GraphSAGE 2-layer, N=100000, E=1200000, D: 64 -> 64 -> 32, fp32 in/out.
// R13: atomic-free graph build. Established empirically (R6/R10/R11/R12):
// device-scope atomics bypass the per-XCD L2 and cost ~32-40B memory-side
// write traffic EACH, immune to locality tricks (48-56MB for 4.8MB payload).
// Fix: eliminate per-edge global atomics entirely.
//   Phase A compact_edges64: block histograms its 1280 edges into 64 LDS
//     bins, reserves space in 64 sub-partition queues with 64 global
//     atomics PER BLOCK (60K total, not 1.2M), writes (src,dst) runs.
//   Phase B csr_build_local: block p reads only queue p (~150KB), builds
//     an exact CSR in LDS (LDS atomics + LDS scan), stages neighbors in
//     96KB LDS, streams out coalesced. info[n]=(start,deg) for gather.
// Gather: exact-CSR 8-rows-in-flight uint4 (R9). Dense: 4-wave j-split
// (R8). bf16 activations (R6).

#define D1 64
#define NQ 64                // sub-partition queues
#define SUBN 1563            // ceil(N/64); d/SUBN <= 63 for d < 100032
#define QCAP64 20480         // queue cap; avg 18750, sigma ~136
#define LCAP 24576           // LDS nbr staging (96KB), >= QCAP64
#define BE 1280              // edges per phase-A block (256 thr x 5)

static __device__ __forceinline__ float bf2f(ushort u) {
    unsigned int x = ((unsigned int)u) << 16;
    return __uint_as_float(x);
}
static __device__ __forceinline__ ushort f2bf(float f) {
    union { __hip_bfloat16 b; ushort u; } cv;
    cv.b = __float2bfloat16(f);   // RNE
    return cv.u;
}
static __device__ __forceinline__ float lo2f(unsigned u) {
    return __uint_as_float(u << 16);
}
static __device__ __forceinline__ float hi2f(unsigned u) {
    return __uint_as_float(u & 0xffff0000u);
}
static __device__ __forceinline__ unsigned packbf(float x, float y) {
    return (unsigned)f2bf(x) | ((unsigned)f2bf(y) << 16);
}

// ---- phase A: compact edges into 64 sub-partition queues ----------------

__global__ __launch_bounds__(256)
void compact_edges64(const int* __restrict__ src, const int* __restrict__ dst,
                     int* __restrict__ tail, int2* __restrict__ queue, int E) {
    __shared__ int hist[NQ];
    __shared__ int base[NQ];
    int tid = threadIdx.x;
    int bstart = blockIdx.x * BE;

    int ds[5], ss[5], pp[5];
    if (tid < NQ) hist[tid] = 0;
    __syncthreads();
    #pragma unroll
    for (int k = 0; k < 5; ++k) {
        int e = bstart + k * 256 + tid;
        int d = -1, s = 0;
        if (e < E) { d = dst[e]; s = src[e]; }
        ds[k] = d; ss[k] = s;
        int p = (d >= 0) ? (d / SUBN) : -1;
        pp[k] = p;
        if (p >= 0) atomicAdd(&hist[p], 1);       // LDS atomic
    }
    __syncthreads();
    if (tid < NQ) {
        base[tid] = atomicAdd(&tail[tid], hist[tid]);   // 64 global atomics
        hist[tid] = 0;                                   // reuse as cursor
    }
    __syncthreads();
    #pragma unroll
    for (int k = 0; k < 5; ++k) {
        int p = pp[k];
        if (p >= 0) {
            int pos = base[p] + atomicAdd(&hist[p], 1);  // LDS atomic
            if (pos < QCAP64)
                queue[(size_t)p * QCAP64 + pos] = make_int2(ss[k], ds[k]);
        }
    }
}

// ---- phase B: per-sub-partition exact CSR built entirely in LDS ---------

__global__ __launch_bounds__(256)
void csr_build_local(const int2* __restrict__ queue, const int* __restrict__ tail,
                     int2* __restrict__ info, int* __restrict__ nbr, int N) {
    __shared__ int lcnt[1792];           // 7*256 >= SUBN
    __shared__ int psum[256];
    __shared__ int lnbr[LCAP];           // 96KB staging
    int tid = threadIdx.x;
    int p = blockIdx.x;
    int lo = p * SUBN;
    int nt = min(tail[p], QCAP64);
    const int2* q = queue + (size_t)p * QCAP64;
    int gbase = p * LCAP;

    for (int i = tid; i < 1792; i += 256) lcnt[i] = 0;
    __syncthreads();
    for (int e = tid; e < nt; e += 256) {
        int d = q[e].y;
        atomicAdd(&lcnt[d - lo], 1);     // LDS atomic
    }
    __syncthreads();

    // exclusive scan of lcnt[0..SUBN): thread t owns elements t*7..t*7+6
    int loc[7];
    int s = 0;
    #pragma unroll
    for (int k = 0; k < 7; ++k) { loc[k] = s; s += lcnt[tid * 7 + k]; }
    psum[tid] = s;
    __syncthreads();
    for (int off = 1; off < 256; off <<= 1) {
        int a = (tid >= off) ? psum[tid - off] : 0;
        __syncthreads();
        psum[tid] += a;
        __syncthreads();
    }
    int pbase = psum[tid] - s;           // exclusive over threads

    // write info[n] = (global start, deg); convert lcnt to local cursors
    #pragma unroll
    for (int k = 0; k < 7; ++k) {
        int li = tid * 7 + k;
        int excl = pbase + loc[k];
        int deg = lcnt[li];              // own element: no race with write below
        int n = lo + li;
        if (li < SUBN && n < N) info[n] = make_int2(gbase + excl, deg);
        lcnt[li] = excl;                 // local cursor
    }
    __syncthreads();

    for (int e = tid; e < nt; e += 256) {
        int2 pr = q[e];
        int pos = atomicAdd(&lcnt[pr.y - lo], 1);   // LDS atomic
        lnbr[pos] = pr.x;
    }
    __syncthreads();

    for (int i = tid; i < nt; i += 256)  // coalesced copy-out
        nbr[gbase + i] = lnbr[i];
}

// ---- fp32 -> bf16 activation convert ------------------------------------

__global__ __launch_bounds__(256)
void cvt_bf16(const float* __restrict__ in, ushort* __restrict__ outp, int n4) {
    int i = blockIdx.x * 256 + threadIdx.x;   // one float4 -> ushort4
    if (i < n4) {
        float4 v = *(const float4*)&in[(size_t)i * 4];
        ushort4 u;
        u.x = f2bf(v.x); u.y = f2bf(v.y); u.z = f2bf(v.z); u.w = f2bf(v.w);
        *(ushort4*)&outp[(size_t)i * 4] = u;
    }
}

// ---- gather: mean of bf16 neighbor rows. Wave per node. ------------------
// Lane (r,c) = (lane>>3, lane&7): slot r covers neighbor i+r, lane loads
// uint4 = 8 bf16 at quad c -> one instruction fetches 8 full rows (1KB).
// Unroll x2 (16 rows in flight). Reduce slots via shfl_xor 8/16/32.

#define ACC8(u) do { \
    a0 += lo2f((u).x); a1 += hi2f((u).x); \
    a2 += lo2f((u).y); a3 += hi2f((u).y); \
    a4 += lo2f((u).z); a5 += hi2f((u).z); \
    a6 += lo2f((u).w); a7 += hi2f((u).w); } while (0)

__global__ __launch_bounds__(256)
void gather_mean8(const ushort* __restrict__ feat,
                  const int2* __restrict__ info,
                  const int* __restrict__ nbr,
                  ushort* __restrict__ mean, int N) {
    int wid  = (blockIdx.x * 256 + threadIdx.x) >> 6;
    int lane = threadIdx.x & 63;
    if (wid >= N) return;
    int2 ii = info[wid];
    int deg = ii.y;
    int m = deg;
    const int* nb = nbr + ii.x;
    int r = lane >> 3;          // neighbor slot 0..7
    int c = lane & 7;           // uint4 quad within 64-feature row
    const uint4* f4 = (const uint4*)feat;

    float a0 = 0, a1 = 0, a2 = 0, a3 = 0, a4 = 0, a5 = 0, a6 = 0, a7 = 0;
    int i = 0;
    for (; i + 16 <= m; i += 16) {
        int e0 = nb[i + r];
        int e1 = nb[i + 8 + r];
        uint4 u0 = f4[(size_t)e0 * 8 + c];
        uint4 u1 = f4[(size_t)e1 * 8 + c];
        ACC8(u0);
        ACC8(u1);
    }
    if (i + 8 <= m) {
        int e0 = nb[i + r];
        uint4 u0 = f4[(size_t)e0 * 8 + c];
        ACC8(u0);
        i += 8;
    }
    if (i < m) {
        int idx = i + r;
        int e = nb[(idx < m) ? idx : (m - 1)];
        uint4 u = f4[(size_t)e * 8 + c];
        if (idx < m) ACC8(u);
    }

    // reduce across the 8 slots (lane bits 3,4,5)
    a0 += __shfl_xor(a0, 8, 64); a0 += __shfl_xor(a0, 16, 64); a0 += __shfl_xor(a0, 32, 64);
    a1 += __shfl_xor(a1, 8, 64); a1 += __shfl_xor(a1, 16, 64); a1 += __shfl_xor(a1, 32, 64);
    a2 += __shfl_xor(a2, 8, 64); a2 += __shfl_xor(a2, 16, 64); a2 += __shfl_xor(a2, 32, 64);
    a3 += __shfl_xor(a3, 8, 64); a3 += __shfl_xor(a3, 16, 64); a3 += __shfl_xor(a3, 32, 64);
    a4 += __shfl_xor(a4, 8, 64); a4 += __shfl_xor(a4, 16, 64); a4 += __shfl_xor(a4, 32, 64);
    a5 += __shfl_xor(a5, 8, 64); a5 += __shfl_xor(a5, 16, 64); a5 += __shfl_xor(a5, 32, 64);
    a6 += __shfl_xor(a6, 8, 64); a6 += __shfl_xor(a6, 16, 64); a6 += __shfl_xor(a6, 32, 64);
    a7 += __shfl_xor(a7, 8, 64); a7 += __shfl_xor(a7, 16, 64); a7 += __shfl_xor(a7, 32, 64);

    if (r == 0) {               // lanes 0..7 write the 128B mean row
        float inv = 1.0f / fmaxf((float)deg, 1.0f);
        uint4 o;
        o.x = packbf(a0 * inv, a1 * inv);
        o.y = packbf(a2 * inv, a3 * inv);
        o.z = packbf(a4 * inv, a5 * inv);
        o.w = packbf(a6 * inv, a7 * inv);
        ((uint4*)mean)[(size_t)wid * 8 + c] = o;
    }
}

// ---- dense: out[n][j] = act(sum_k Am[n][k] Wm[k][j] + Ax[n][k] Wx[k][j] + b[j])
// Block = 256 threads = 64 nodes; lane = node. Wave w computes j-slice
// [w*DOUT/4, (w+1)*DOUT/4). Shared bf16 A-tile ta[128][66] (Am k=0..63,
// Ax k=64..127). Weights wave-uniform -> scalar loads. Epilogue reuses
// LDS as fp32 [DOUT][65] transpose tile.

#define TA_STRIDE 66

template <int DOUT, bool RELU, bool OUTBF>
__global__ __launch_bounds__(256)
void dense_sage(const ushort* __restrict__ Am,    // mean [N][64] bf16
                const ushort* __restrict__ Ax,    // x or h [N][64] bf16
                const float* __restrict__ Wm,     // [64][DOUT]
                const float* __restrict__ Wx,     // [64][DOUT]
                const float* __restrict__ bias,   // [DOUT]
                void* __restrict__ outp, int N) {
    constexpr int JW = DOUT / 4;                  // j per wave: 16 or 8
    __shared__ char smraw[128 * TA_STRIDE * 2];   // 16.9 KB (>= DOUT*65*4)
    ushort* ta = (ushort*)smraw;
    float*  to = (float*)smraw;

    int tid  = threadIdx.x;
    int w    = tid >> 6;
    int lane = tid & 63;
    int n0 = blockIdx.x * 64;

    // stage 128 logical rows (64 Am + 64 Ax) x 64 cols, transposed:
    // ta[k][node], k = (isAx ? 64 : 0) + col. 16 threads cover one 128B row.
    #pragma unroll
    for (int i = 0; i < 8; ++i) {
        int flat = i * 256 + tid;        // 0..2047 ushort4-chunks
        int row  = flat >> 4;            // 0..127
        int c4   = (flat & 15) * 4;      // 0..60
        const ushort* A = (row < 64) ? Am : Ax;
        int node = row & 63;
        int grow = n0 + node;
        ushort4 u = make_ushort4(0, 0, 0, 0);
        if (grow < N) u = *(const ushort4*)&A[(size_t)grow * D1 + c4];
        int kb = ((row < 64) ? 0 : 64) + c4;
        ta[(kb + 0) * TA_STRIDE + node] = u.x;
        ta[(kb + 1) * TA_STRIDE + node] = u.y;
        ta[(kb + 2) * TA_STRIDE + node] = u.z;
        ta[(kb + 3) * TA_STRIDE + node] = u.w;
    }
    __syncthreads();

    int jb = __builtin_amdgcn_readfirstlane(w * JW);
    float c[JW];
    #pragma unroll
    for (int j = 0; j < JW; ++j) c[j] = bias[jb + j];

    #pragma unroll 4
    for (int k = 0; k < 64; ++k) {
        float a = bf2f(ta[k * TA_STRIDE + lane]);
        #pragma unroll
        for (int j = 0; j < JW; ++j)
            c[j] = fmaf(a, Wm[k * DOUT + jb + j], c[j]);   // wave-uniform idx
    }
    #pragma unroll 4
    for (int k = 0; k < 64; ++k) {
        float a = bf2f(ta[(64 + k) * TA_STRIDE + lane]);
        #pragma unroll
        for (int j = 0; j < JW; ++j)
            c[j] = fmaf(a, Wx[k * DOUT + jb + j], c[j]);
    }

    if (RELU) {
        #pragma unroll
        for (int j = 0; j < JW; ++j) c[j] = fmaxf(c[j], 0.0f);
    }

    __syncthreads();   // A-tile fully consumed -> reuse LDS as out-tile
    #pragma unroll
    for (int j = 0; j < JW; ++j) to[(jb + j) * 65 + lane] = c[j];
    __syncthreads();

    // coalesced store: 64 rows x DOUT, vec4 chunks
    #pragma unroll
    for (int i = 0; i < DOUT / 16; ++i) {
        int flat = i * 256 + tid;            // quad index
        int node = flat / (DOUT / 4);
        int q    = flat % (DOUT / 4);
        int grow = n0 + node;
        if (grow < N) {
            float vx = to[(q * 4 + 0) * 65 + node];
            float vy = to[(q * 4 + 1) * 65 + node];
            float vz = to[(q * 4 + 2) * 65 + node];
            float vw = to[(q * 4 + 3) * 65 + node];
            size_t o = (size_t)grow * DOUT + q * 4;
            if (OUTBF) {
                ushort4 u;
                u.x = f2bf(vx); u.y = f2bf(vy); u.z = f2bf(vz); u.w = f2bf(vw);
                *(ushort4*)&((ushort*)outp)[o] = u;
            } else {
                *(float4*)&((float*)outp)[o] = make_float4(vx, vy, vz, vw);
            }
        }
    }
}

// ---- launch -------------------------------------------------------------

extern "C" void kernel_launch(void* const* d_in, const int* in_sizes, int n_in,
                              void* d_out, int out_size, void* d_ws, size_t ws_size,
                              hipStream_t stream) {
    const float* x   = (const float*)d_in[0];
    const int*   ei  = (const int*)d_in[1];
    const float* W1l = (const float*)d_in[2];
    const float* W1r = (const float*)d_in[3];
    const float* b1  = (const float*)d_in[4];
    const float* W2l = (const float*)d_in[5];
    const float* W2r = (const float*)d_in[6];
    const float* b2  = (const float*)d_in[7];
    float* out = (float*)d_out;

    int N = in_sizes[0] / D1;
    int E = in_sizes[1] / 2;
    const int* src = ei;
    const int* dst = ei + E;

    char* ws = (char*)d_ws;
    auto alignup = [](size_t v) { return (v + 255) & ~(size_t)255; };
    size_t off = 0;
    int*    tail  = (int*)(ws + off);    off += alignup(NQ * 4);
    int2*   queue = (int2*)(ws + off);   off += alignup((size_t)NQ * QCAP64 * 8);
    int*    nbr   = (int*)(ws + off);    off += alignup((size_t)NQ * LCAP * 4);
    int2*   info  = (int2*)(ws + off);   off += alignup((size_t)N * 8);
    ushort* xh    = (ushort*)(ws + off); off += alignup((size_t)N * D1 * 2);
    ushort* hh    = (ushort*)(ws + off); off += alignup((size_t)N * D1 * 2);
    // layer-1 mean lives in d_out (fully overwritten by dense2 at the end);
    // layer-2 mean reuses xh (dead after dense1).
    ushort* mean1 = (ushort*)d_out;      // N*64*2B = 12.8MB == out_size bytes
    ushort* mean2 = xh;

    int gb = (N + 3) / 4;         // gather: wave per node, 4 waves/block
    int db = (N + 63) / 64;       // dense: 64 nodes/block, 4 j-slice waves
    int cb = ((N * D1 / 4) + 255) / 256;
    int ab = (E + BE - 1) / BE;   // phase-A blocks (938)

    hipMemsetAsync(tail, 0, NQ * 4, stream);
    compact_edges64<<<ab, 256, 0, stream>>>(src, dst, tail, queue, E);
    csr_build_local<<<NQ, 256, 0, stream>>>(queue, tail, info, nbr, N);
    cvt_bf16<<<cb, 256, 0, stream>>>(x, xh, N * D1 / 4);

    gather_mean8<<<gb, 256, 0, stream>>>(xh, info, nbr, mean1, N);
    dense_sage<64, true, true ><<<db, 256, 0, stream>>>(mean1, xh, W1l, W1r, b1, hh, N);
    gather_mean8<<<gb, 256, 0, stream>>>(hh, info, nbr, mean2, N);
    dense_sage<32, false, false><<<db, 256, 0, stream>>>(mean2, hh, W2l, W2r, b2, out, N);
}

// Round 14
// 151.225 us; speedup vs baseline: 1.3093x; 1.2572x over previous
//
#include <hip/hip_runtime.h>
#include <hip/hip_bf16.h>

// GraphSAGE 2-layer, N=100000, E=1200000, D: 64 -> 64 -> 32, fp32 in/out.
// R14: R13 (atomic-free LDS build) with three fixes:
//  - NQ 64->256 sub-partitions: csr_build gets 256 blocks x 36KB LDS
//    (was 64 x 106KB = quarter-GPU, 1 blk/CU) -> full width.
//  - memset dispatch deleted: tail zero + sentinel-row init folded into
//    cvt_bf16_init (stream order guarantees visibility).
//  - nbr lists padded to 8 with sentinel index N (zero feature row):
//    gather tail predication gone, all 8-row batches full, pad loads hit
//    one L1-resident zero line.
// Established (R6/R10/R11/R12): per-edge device atomics cost ~32-40B
// memory-side traffic each, immune to locality -> build uses LDS atomics
// + 256 global reservations per block only.

#define D1 64
#define NQ 256               // sub-partition queues (== blockDim for compact)
#define SUBN 391             // ceil(N/256); d/SUBN <= 255 for d < 100096
#define QCAP 5632            // per-queue cap; avg 4687, sigma ~68 (13+ sigma)
#define LCAP 8448            // padded staging cap >= QCAP + SUBN*7 = 8369
#define BE 5120              // edges per phase-A block (2 streaming passes)

static __device__ __forceinline__ float bf2f(ushort u) {
    unsigned int x = ((unsigned int)u) << 16;
    return __uint_as_float(x);
}
static __device__ __forceinline__ ushort f2bf(float f) {
    union { __hip_bfloat16 b; ushort u; } cv;
    cv.b = __float2bfloat16(f);   // RNE
    return cv.u;
}
static __device__ __forceinline__ float lo2f(unsigned u) {
    return __uint_as_float(u << 16);
}
static __device__ __forceinline__ float hi2f(unsigned u) {
    return __uint_as_float(u & 0xffff0000u);
}
static __device__ __forceinline__ unsigned packbf(float x, float y) {
    return (unsigned)f2bf(x) | ((unsigned)f2bf(y) << 16);
}

// ---- phase A: compact edges into 256 sub-partition queues ----------------
// Two streaming passes (count, then write); 256 global atomics per block.

__global__ __launch_bounds__(256)
void compact_edges256(const int* __restrict__ src, const int* __restrict__ dst,
                      int* __restrict__ tail, int2* __restrict__ queue, int E) {
    __shared__ int hist[NQ];
    __shared__ int base[NQ];
    int tid = threadIdx.x;
    int e0 = blockIdx.x * BE;
    int e1 = min(E, e0 + BE);

    hist[tid] = 0;
    __syncthreads();
    for (int e = e0 + tid; e < e1; e += 256)
        atomicAdd(&hist[dst[e] / SUBN], 1);          // LDS atomic
    __syncthreads();
    base[tid] = atomicAdd(&tail[tid], hist[tid]);    // 256 global atomics/blk
    hist[tid] = 0;                                   // reuse as cursor
    __syncthreads();
    for (int e = e0 + tid; e < e1; e += 256) {
        int d = dst[e];
        int s = src[e];
        int p = d / SUBN;
        int pos = base[p] + atomicAdd(&hist[p], 1);  // LDS atomic
        if (pos < QCAP) queue[(size_t)p * QCAP + pos] = make_int2(s, d);
    }
}

// ---- phase B: per-sub-partition exact CSR built entirely in LDS ---------
// Lists padded to multiple of 8 with sentinel N (zero feature row).

__global__ __launch_bounds__(256)
void csr_build_local(const int2* __restrict__ queue, const int* __restrict__ tail,
                     int2* __restrict__ info, int* __restrict__ nbr, int N) {
    __shared__ int lcnt[512];            // >= SUBN
    __shared__ int psum[256];
    __shared__ int lnbr[LCAP];           // 33.8 KB staging
    int tid = threadIdx.x;
    int p = blockIdx.x;
    int lo = p * SUBN;
    int nt = min(tail[p], QCAP);
    const int2* q = queue + (size_t)p * QCAP;
    int gbase = p * LCAP;

    lcnt[tid] = 0; lcnt[tid + 256] = 0;
    __syncthreads();
    for (int e = tid; e < nt; e += 256)
        atomicAdd(&lcnt[q[e].y - lo], 1);            // LDS atomic
    __syncthreads();

    // exclusive scan over PADDED sizes; thread owns elements 2t, 2t+1
    int d0 = lcnt[2 * tid], d1 = lcnt[2 * tid + 1];
    int p0 = (d0 + 7) & ~7, p1 = (d1 + 7) & ~7;
    int s = p0 + p1;
    psum[tid] = s;
    __syncthreads();
    for (int off = 1; off < 256; off <<= 1) {
        int a = (tid >= off) ? psum[tid - off] : 0;
        __syncthreads();
        psum[tid] += a;
        __syncthreads();
    }
    int st0 = psum[tid] - s;
    int st1 = st0 + p0;
    int ptot = psum[255];

    {
        int li = 2 * tid, n = lo + li;
        if (li < SUBN && n < N) info[n] = make_int2(gbase + st0, d0);
        lcnt[li] = st0;                  // local cursor
        li = 2 * tid + 1; n = lo + li;
        if (li < SUBN && n < N) info[n] = make_int2(gbase + st1, d1);
        lcnt[li] = st1;
    }
    __syncthreads();

    for (int e = tid; e < nt; e += 256) {
        int2 pr = q[e];
        int pos = atomicAdd(&lcnt[pr.y - lo], 1);    // LDS atomic
        lnbr[pos] = pr.x;
    }
    __syncthreads();

    // fill pad slots with sentinel N
    for (int j = st0 + d0; j < st0 + p0; ++j) lnbr[j] = N;
    for (int j = st1 + d1; j < st1 + p1; ++j) lnbr[j] = N;
    __syncthreads();

    for (int i = tid; i < ptot; i += 256)            // coalesced copy-out
        nbr[gbase + i] = lnbr[i];
}

// ---- fp32 -> bf16 convert + pipeline init (tail zero, sentinel rows) ----

__global__ __launch_bounds__(256)
void cvt_bf16_init(const float* __restrict__ in, ushort* __restrict__ xh,
                   ushort* __restrict__ hh, int* __restrict__ tail,
                   int n4, int N) {
    int i = blockIdx.x * 256 + threadIdx.x;   // one float4 -> ushort4
    if (i < n4) {
        float4 v = *(const float4*)&in[(size_t)i * 4];
        ushort4 u;
        u.x = f2bf(v.x); u.y = f2bf(v.y); u.z = f2bf(v.z); u.w = f2bf(v.w);
        *(ushort4*)&xh[(size_t)i * 4] = u;
    }
    if (blockIdx.x == 0) tail[threadIdx.x] = 0;               // NQ == 256
    if (blockIdx.x == 1 && threadIdx.x < D1) {                // zero row N
        xh[(size_t)N * D1 + threadIdx.x] = 0;
        hh[(size_t)N * D1 + threadIdx.x] = 0;
    }
}

// ---- gather: mean of bf16 neighbor rows. Wave per node. ------------------
// Lists are 8-padded: every batch is a full 8-row 1KB fetch, no tail mask.

#define ACC8(u) do { \
    a0 += lo2f((u).x); a1 += hi2f((u).x); \
    a2 += lo2f((u).y); a3 += hi2f((u).y); \
    a4 += lo2f((u).z); a5 += hi2f((u).z); \
    a6 += lo2f((u).w); a7 += hi2f((u).w); } while (0)

__global__ __launch_bounds__(256)
void gather_mean8(const ushort* __restrict__ feat,
                  const int2* __restrict__ info,
                  const int* __restrict__ nbr,
                  ushort* __restrict__ mean, int N) {
    int wid  = (blockIdx.x * 256 + threadIdx.x) >> 6;
    int lane = threadIdx.x & 63;
    if (wid >= N) return;
    int2 ii = info[wid];
    int deg = ii.y;
    int m8 = (deg + 7) & ~7;
    const int* nb = nbr + ii.x;
    int r = lane >> 3;          // neighbor slot 0..7
    int c = lane & 7;           // uint4 quad within 64-feature row
    const uint4* f4 = (const uint4*)feat;

    float a0 = 0, a1 = 0, a2 = 0, a3 = 0, a4 = 0, a5 = 0, a6 = 0, a7 = 0;
    int i = 0;
    for (; i + 16 <= m8; i += 16) {
        int e0 = nb[i + r];
        int e1 = nb[i + 8 + r];
        uint4 u0 = f4[(size_t)e0 * 8 + c];
        uint4 u1 = f4[(size_t)e1 * 8 + c];
        ACC8(u0);
        ACC8(u1);
    }
    if (i < m8) {
        int e0 = nb[i + r];
        uint4 u0 = f4[(size_t)e0 * 8 + c];
        ACC8(u0);
    }

    // reduce across the 8 slots (lane bits 3,4,5)
    a0 += __shfl_xor(a0, 8, 64); a0 += __shfl_xor(a0, 16, 64); a0 += __shfl_xor(a0, 32, 64);
    a1 += __shfl_xor(a1, 8, 64); a1 += __shfl_xor(a1, 16, 64); a1 += __shfl_xor(a1, 32, 64);
    a2 += __shfl_xor(a2, 8, 64); a2 += __shfl_xor(a2, 16, 64); a2 += __shfl_xor(a2, 32, 64);
    a3 += __shfl_xor(a3, 8, 64); a3 += __shfl_xor(a3, 16, 64); a3 += __shfl_xor(a3, 32, 64);
    a4 += __shfl_xor(a4, 8, 64); a4 += __shfl_xor(a4, 16, 64); a4 += __shfl_xor(a4, 32, 64);
    a5 += __shfl_xor(a5, 8, 64); a5 += __shfl_xor(a5, 16, 64); a5 += __shfl_xor(a5, 32, 64);
    a6 += __shfl_xor(a6, 8, 64); a6 += __shfl_xor(a6, 16, 64); a6 += __shfl_xor(a6, 32, 64);
    a7 += __shfl_xor(a7, 8, 64); a7 += __shfl_xor(a7, 16, 64); a7 += __shfl_xor(a7, 32, 64);

    if (r == 0) {               // lanes 0..7 write the 128B mean row
        float inv = 1.0f / fmaxf((float)deg, 1.0f);
        uint4 o;
        o.x = packbf(a0 * inv, a1 * inv);
        o.y = packbf(a2 * inv, a3 * inv);
        o.z = packbf(a4 * inv, a5 * inv);
        o.w = packbf(a6 * inv, a7 * inv);
        ((uint4*)mean)[(size_t)wid * 8 + c] = o;
    }
}

// ---- dense: out[n][j] = act(sum_k Am[n][k] Wm[k][j] + Ax[n][k] Wx[k][j] + b[j])
// Block = 256 threads = 64 nodes; lane = node. Wave w computes j-slice
// [w*DOUT/4, (w+1)*DOUT/4). Shared bf16 A-tile ta[128][66] (Am k=0..63,
// Ax k=64..127). Weights wave-uniform -> scalar loads. Epilogue reuses
// LDS as fp32 [DOUT][65] transpose tile.

#define TA_STRIDE 66

template <int DOUT, bool RELU, bool OUTBF>
__global__ __launch_bounds__(256)
void dense_sage(const ushort* __restrict__ Am,    // mean [N][64] bf16
                const ushort* __restrict__ Ax,    // x or h [N][64] bf16
                const float* __restrict__ Wm,     // [64][DOUT]
                const float* __restrict__ Wx,     // [64][DOUT]
                const float* __restrict__ bias,   // [DOUT]
                void* __restrict__ outp, int N) {
    constexpr int JW = DOUT / 4;                  // j per wave: 16 or 8
    __shared__ char smraw[128 * TA_STRIDE * 2];   // 16.9 KB (>= DOUT*65*4)
    ushort* ta = (ushort*)smraw;
    float*  to = (float*)smraw;

    int tid  = threadIdx.x;
    int w    = tid >> 6;
    int lane = tid & 63;
    int n0 = blockIdx.x * 64;

    // stage 128 logical rows (64 Am + 64 Ax) x 64 cols, transposed:
    // ta[k][node], k = (isAx ? 64 : 0) + col. 16 threads cover one 128B row.
    #pragma unroll
    for (int i = 0; i < 8; ++i) {
        int flat = i * 256 + tid;        // 0..2047 ushort4-chunks
        int row  = flat >> 4;            // 0..127
        int c4   = (flat & 15) * 4;      // 0..60
        const ushort* A = (row < 64) ? Am : Ax;
        int node = row & 63;
        int grow = n0 + node;
        ushort4 u = make_ushort4(0, 0, 0, 0);
        if (grow < N) u = *(const ushort4*)&A[(size_t)grow * D1 + c4];
        int kb = ((row < 64) ? 0 : 64) + c4;
        ta[(kb + 0) * TA_STRIDE + node] = u.x;
        ta[(kb + 1) * TA_STRIDE + node] = u.y;
        ta[(kb + 2) * TA_STRIDE + node] = u.z;
        ta[(kb + 3) * TA_STRIDE + node] = u.w;
    }
    __syncthreads();

    int jb = __builtin_amdgcn_readfirstlane(w * JW);
    float c[JW];
    #pragma unroll
    for (int j = 0; j < JW; ++j) c[j] = bias[jb + j];

    #pragma unroll 4
    for (int k = 0; k < 64; ++k) {
        float a = bf2f(ta[k * TA_STRIDE + lane]);
        #pragma unroll
        for (int j = 0; j < JW; ++j)
            c[j] = fmaf(a, Wm[k * DOUT + jb + j], c[j]);   // wave-uniform idx
    }
    #pragma unroll 4
    for (int k = 0; k < 64; ++k) {
        float a = bf2f(ta[(64 + k) * TA_STRIDE + lane]);
        #pragma unroll
        for (int j = 0; j < JW; ++j)
            c[j] = fmaf(a, Wx[k * DOUT + jb + j], c[j]);
    }

    if (RELU) {
        #pragma unroll
        for (int j = 0; j < JW; ++j) c[j] = fmaxf(c[j], 0.0f);
    }

    __syncthreads();   // A-tile fully consumed -> reuse LDS as out-tile
    #pragma unroll
    for (int j = 0; j < JW; ++j) to[(jb + j) * 65 + lane] = c[j];
    __syncthreads();

    // coalesced store: 64 rows x DOUT, vec4 chunks
    #pragma unroll
    for (int i = 0; i < DOUT / 16; ++i) {
        int flat = i * 256 + tid;            // quad index
        int node = flat / (DOUT / 4);
        int q    = flat % (DOUT / 4);
        int grow = n0 + node;
        if (grow < N) {
            float vx = to[(q * 4 + 0) * 65 + node];
            float vy = to[(q * 4 + 1) * 65 + node];
            float vz = to[(q * 4 + 2) * 65 + node];
            float vw = to[(q * 4 + 3) * 65 + node];
            size_t o = (size_t)grow * DOUT + q * 4;
            if (OUTBF) {
                ushort4 u;
                u.x = f2bf(vx); u.y = f2bf(vy); u.z = f2bf(vz); u.w = f2bf(vw);
                *(ushort4*)&((ushort*)outp)[o] = u;
            } else {
                *(float4*)&((float*)outp)[o] = make_float4(vx, vy, vz, vw);
            }
        }
    }
}

// ---- launch -------------------------------------------------------------

extern "C" void kernel_launch(void* const* d_in, const int* in_sizes, int n_in,
                              void* d_out, int out_size, void* d_ws, size_t ws_size,
                              hipStream_t stream) {
    const float* x   = (const float*)d_in[0];
    const int*   ei  = (const int*)d_in[1];
    const float* W1l = (const float*)d_in[2];
    const float* W1r = (const float*)d_in[3];
    const float* b1  = (const float*)d_in[4];
    const float* W2l = (const float*)d_in[5];
    const float* W2r = (const float*)d_in[6];
    const float* b2  = (const float*)d_in[7];
    float* out = (float*)d_out;

    int N = in_sizes[0] / D1;
    int E = in_sizes[1] / 2;
    const int* src = ei;
    const int* dst = ei + E;

    char* ws = (char*)d_ws;
    auto alignup = [](size_t v) { return (v + 255) & ~(size_t)255; };
    size_t off = 0;
    int*    tail  = (int*)(ws + off);    off += alignup(NQ * 4);
    int2*   queue = (int2*)(ws + off);   off += alignup((size_t)NQ * QCAP * 8);
    int*    nbr   = (int*)(ws + off);    off += alignup((size_t)NQ * LCAP * 4);
    int2*   info  = (int2*)(ws + off);   off += alignup((size_t)N * 8);
    ushort* xh    = (ushort*)(ws + off); off += alignup((size_t)(N + 1) * D1 * 2);
    ushort* hh    = (ushort*)(ws + off); off += alignup((size_t)(N + 1) * D1 * 2);
    // layer-1 mean lives in d_out (fully overwritten by dense2 at the end);
    // layer-2 mean reuses xh rows [0,N) (dead after dense1).
    ushort* mean1 = (ushort*)d_out;      // N*64*2B = 12.8MB == out_size bytes
    ushort* mean2 = xh;

    int gb = (N + 3) / 4;         // gather: wave per node, 4 waves/block
    int db = (N + 63) / 64;       // dense: 64 nodes/block, 4 j-slice waves
    int cb = ((N * D1 / 4) + 255) / 256;
    int ab = (E + BE - 1) / BE;   // phase-A blocks (235)

    cvt_bf16_init<<<cb, 256, 0, stream>>>(x, xh, hh, tail, N * D1 / 4, N);
    compact_edges256<<<ab, 256, 0, stream>>>(src, dst, tail, queue, E);
    csr_build_local<<<NQ, 256, 0, stream>>>(queue, tail, info, nbr, N);

    gather_mean8<<<gb, 256, 0, stream>>>(xh, info, nbr, mean1, N);
    dense_sage<64, true, true ><<<db, 256, 0, stream>>>(mean1, xh, W1l, W1r, b1, hh, N);
    gather_mean8<<<gb, 256, 0, stream>>>(hh, info, nbr, mean2, N);
    dense_sage<32, false, false><<<db, 256, 0, stream>>>(mean2, hh, W2l, W2r, b2, out, N);
}